// Round 1
// baseline (151.250 us; speedup 1.0000x reference)
//
#include <hip/hip_runtime.h>

#define H   384
#define W   384
#define HW  (H*W)
#define A2  25
#define BLK 192   // 3 waves: one per output color channel

// R3: scalarize wave-uniform state.
//  - c = tid>>6 is wave-uniform (64 lanes per color) -> readfirstlane so all
//    plane/row/output pointers become SGPR saddr-form; loads/stores carry a
//    single 32-bit voffset (colx/pix) instead of per-lane 64-bit address math.
//  - i (row) is block-uniform -> ay weight tables are wave-uniform floats;
//    readfirstlane them into SGPRs (v_fma allows 1 SGPR src).
//  - off[] size_t[9] replaced by 3 int col offsets + uniform row offsets.
// Compute structure and FP expression order identical to the verified R2 kernel.

__device__ __forceinline__ float rfl_f(float x) {
    return __int_as_float(__builtin_amdgcn_readfirstlane(__float_as_int(x)));
}

__global__ __launch_bounds__(BLK) void multilayer_tap3(
    const float* __restrict__ layers, float* __restrict__ out)
{
    const int lane = threadIdx.x & 63;
    const int c    = __builtin_amdgcn_readfirstlane((int)(threadIdx.x >> 6)); // 0..2, wave-uniform
    const int b    = blockIdx.x;
    const int i    = b / 6;                     // row (block-uniform)
    const int j    = (b - i * 6) * 64 + lane;   // col (per-lane)

    // ---- setup: 3-tap weight tables (bitwise identical to verified R2) ----
    const double stepd = 2.0 / 383.0;           // np.linspace(-1,1,384) step
    const double flowx = (double)j * stepd - 1.0;
    const double flowy = (double)i * stepd - 1.0;

    float ax0[5][3], ay0[5][3];   // outer-layer tables (layer0; layer2 = index 4-v)
    float ax1[3],    ay1[3];      // middle layer (shift = 0)

#pragma unroll
    for (int v = 0; v < 5; ++v) {
        const double d = ((-1.0 / 384.0) * (double)(v - 2)) * (-1.0);
        {   // x axis
            const float g = (float)(d + flowx);
            float x   = fminf(fmaxf((g + 1.0f) * 0.5f * 383.0f, 0.0f), 383.0f);
            float x0f = floorf(x);
            float wx  = x - x0f;
            int   dX  = (int)x0f - j + 1;       // 0 or 1
            ax0[v][0] = dX ? 0.0f        : 1.0f - wx;
            ax0[v][1] = dX ? 1.0f - wx   : wx;
            ax0[v][2] = dX ? wx          : 0.0f;
        }
        {   // y axis
            const float g = (float)(d + flowy);
            float y   = fminf(fmaxf((g + 1.0f) * 0.5f * 383.0f, 0.0f), 383.0f);
            float y0f = floorf(y);
            float wy  = y - y0f;
            int   dY  = (int)y0f - i + 1;
            ay0[v][0] = dY ? 0.0f        : 1.0f - wy;
            ay0[v][1] = dY ? 1.0f - wy   : wy;
            ay0[v][2] = dY ? wy          : 0.0f;
        }
    }
    {   // middle layer: d == 0 exactly
        {
            const float g = (float)flowx;
            float x   = fminf(fmaxf((g + 1.0f) * 0.5f * 383.0f, 0.0f), 383.0f);
            float x0f = floorf(x);
            float wx  = x - x0f;
            int   dX  = (int)x0f - j + 1;
            ax1[0] = dX ? 0.0f      : 1.0f - wx;
            ax1[1] = dX ? 1.0f - wx : wx;
            ax1[2] = dX ? wx        : 0.0f;
        }
        {
            const float g = (float)flowy;
            float y   = fminf(fmaxf((g + 1.0f) * 0.5f * 383.0f, 0.0f), 383.0f);
            float y0f = floorf(y);
            float wy  = y - y0f;
            int   dY  = (int)y0f - i + 1;
            ay1[0] = dY ? 0.0f      : 1.0f - wy;
            ay1[1] = dY ? 1.0f - wy : wy;
            ay1[2] = dY ? wy        : 0.0f;
        }
    }

    // y-weights are wave-uniform (depend only on i) -> pin to SGPRs.
#pragma unroll
    for (int v = 0; v < 5; ++v)
#pragma unroll
        for (int t = 0; t < 3; ++t) ay0[v][t] = rfl_f(ay0[v][t]);
#pragma unroll
    for (int t = 0; t < 3; ++t) ay1[t] = rfl_f(ay1[t]);

    // clamped 3x3 neighborhood: uniform row offsets + per-lane col offsets
    const int jm = max(j - 1, 0), jp = min(j + 1, W - 1);
    const int im = max(i - 1, 0), ip = min(i + 1, H - 1);
    const int rowoff[3] = { im * W, i * W, ip * W };   // uniform (SALU)
    const int colx[3]   = { jm, j, jp };               // per-lane, 32-bit

    float acc[A2];
#pragma unroll
    for (int a = 0; a < A2; ++a) acc[a] = 0.0f;

    // nb[buf][layer][dy][dx], software-pipelined over ranks
    float nb[2][3][3][3];

#define LOADN(buf, r_)                                                        \
    {                                                                         \
        const int ch = (r_) * 3 + c;          /* uniform */                   \
        const float* pl0 = layers + (size_t)(ch) * HW;                        \
        const float* pl1 = layers + (size_t)(12 + ch) * HW;                   \
        const float* pl2 = layers + (size_t)(24 + ch) * HW;                   \
        _Pragma("unroll")                                                     \
        for (int dy = 0; dy < 3; ++dy) {                                      \
            const float* r0 = pl0 + rowoff[dy];   /* uniform base */          \
            const float* r1 = pl1 + rowoff[dy];                               \
            const float* r2 = pl2 + rowoff[dy];                               \
            _Pragma("unroll")                                                 \
            for (int dx = 0; dx < 3; ++dx) {                                  \
                nb[buf][0][dy][dx] = r0[colx[dx]];                            \
                nb[buf][1][dy][dx] = r1[colx[dx]];                            \
                nb[buf][2][dy][dx] = r2[colx[dx]];                            \
            }                                                                 \
        }                                                                     \
    }

    LOADN(0, 0)

#pragma unroll
    for (int r = 0; r < 4; ++r) {
        const int cur = r & 1;
        if (r < 3) LOADN((r + 1) & 1, r + 1)

        const float (*n0)[3] = nb[cur][0];
        const float (*n1)[3] = nb[cur][1];
        const float (*n2)[3] = nb[cur][2];

        // middle-layer sample (shared by all 25 views)
        float v1;
        {
            float hy[3];
#pragma unroll
            for (int dy = 0; dy < 3; ++dy)
                hy[dy] = ax1[0] * n1[dy][0] + ax1[1] * n1[dy][1] + ax1[2] * n1[dy][2];
            v1 = ay1[0] * hy[0] + ay1[1] * hy[1] + ay1[2] * hy[2];
        }

#pragma unroll
        for (int al = 0; al < 5; ++al) {
            float h0[3], h2[3];
#pragma unroll
            for (int dy = 0; dy < 3; ++dy) {
                h0[dy] = (ax0[al][0]     * n0[dy][0] + ax0[al][1]     * n0[dy][1] + ax0[al][2]     * n0[dy][2]) * v1;
                h2[dy] =  ax0[4 - al][0] * n2[dy][0] + ax0[4 - al][1] * n2[dy][1] + ax0[4 - al][2] * n2[dy][2];
            }
#pragma unroll
            for (int ak = 0; ak < 5; ++ak) {
                const float s0 = ay0[ak][0]     * h0[0] + ay0[ak][1]     * h0[1] + ay0[ak][2]     * h0[2];
                const float s2 = ay0[4 - ak][0] * h2[0] + ay0[4 - ak][1] * h2[1] + ay0[4 - ak][2] * h2[2];
                acc[ak * 5 + al] += s0 * s2;   // s0 already carries v1: ((w0*w1)*w2)
            }
        }
    }
#undef LOADN

    // out[a][c][i][j], mean over rank = 0.25 * sum
    // base pointer per view is uniform (c scalarized); one 32-bit voffset.
    const int pix = i * W + j;
    float* ob = out + (size_t)c * HW;
#pragma unroll
    for (int a = 0; a < A2; ++a) {
        float* pa = ob + (size_t)a * (3 * HW);   // uniform
        pa[pix] = 0.25f * acc[a];
    }
}

extern "C" void kernel_launch(void* const* d_in, const int* in_sizes, int n_in,
                              void* d_out, int out_size, void* d_ws, size_t ws_size,
                              hipStream_t stream) {
    const float* layers = (const float*)d_in[0];   // [1,3,4,3,384,384] f32
    // d_in[1] (filters) unused: coordinates recomputed analytically (validated R2).
    float* out = (float*)d_out;                    // [1,25,3,384,384] f32

    const int n_blocks = HW / 64;                  // 2304 blocks of 192 threads
    multilayer_tap3<<<n_blocks, BLK, 0, stream>>>(layers, out);
}

// Round 2
// 148.877 us; speedup vs baseline: 1.0159x; 1.0159x over previous
//
#include <hip/hip_runtime.h>

#define H   384
#define W   384
#define HW  (H*W)
#define A2  25
#define BLK 192   // 3 waves: one per output color channel

// R4: exploit tap structure to cut instructions and registers.
//  - Outer shifts v in {0,1,3,4}: sample offset is +-0.4987/+-0.9974 px, so the
//    floor cell is structurally fixed (margin 0.0026 >> 1.4e-4 f32 coord err):
//    true 2-tap (mul+fma) on (jm,j) for v<2 and (j,jp) for v>2. Zero-term
//    elision is exact (fma(a,b,0)=a*b), so results stay bitwise identical.
//  - delta==0 shifts (outer v==2, middle layer) keep a runtime floor dXc/dYc in
//    {0,1}: v==2 stays generic 3-tap; the middle layer becomes a 2x2 gather at
//    runtime-selected addresses (4 loads instead of 9).
//  - y-side weights depend only on i (wave-uniform) -> readfirstlane to SGPR.
//  - Register budget: nb 44 (was 54), tables ~13 VGPR (was 36);
//    __launch_bounds__(192,4) caps at 128 VGPR -> 4 waves/SIMD (was ~2).

__device__ __forceinline__ float rfl_f(float x) {
    return __int_as_float(__builtin_amdgcn_readfirstlane(__float_as_int(x)));
}

__global__ __launch_bounds__(BLK, 4) void multilayer_tap2(
    const float* __restrict__ layers, float* __restrict__ out)
{
    const int lane = threadIdx.x & 63;
    const int c    = __builtin_amdgcn_readfirstlane((int)(threadIdx.x >> 6)); // 0..2
    const int b    = blockIdx.x;
    const int i    = b / 6;                     // row (block-uniform)
    const int j    = (b - i * 6) * 64 + lane;   // col (per-lane)

    // ---- setup: weights (f64 coordinate path mirrors make_filters + _warp) ----
    const double stepd = 2.0 / 383.0;           // np.linspace(-1,1,384) step
    const double flowx = (double)j * stepd - 1.0;
    const double flowy = (double)i * stepd - 1.0;

    float Ax[5], Bx[5];        // 2-tap outer x (slots 2 unused)
    float ax2[3];              // generic 3-tap for v==2 (runtime dXc placement)
    float Axc, Bxc; int dXc;   // middle-layer x pair
    float Ay[5], By[5];        // 2-tap outer y (uniform)
    float ay2[3];              // v==2 y 3-tap (uniform)
    float Ayc, Byc; int dYc;   // middle-layer y pair (uniform)

#pragma unroll
    for (int v = 0; v < 5; ++v) {
        if (v == 2) continue;
        const double d = ((-1.0 / 384.0) * (double)(v - 2)) * (-1.0);
        {   // x axis
            const float g = (float)(d + flowx);
            float x   = fminf(fmaxf((g + 1.0f) * 0.5f * 383.0f, 0.0f), 383.0f);
            float x0f = floorf(x);
            float wx  = x - x0f;
            Ax[v] = 1.0f - wx; Bx[v] = wx;
        }
        {   // y axis
            const float g = (float)(d + flowy);
            float y   = fminf(fmaxf((g + 1.0f) * 0.5f * 383.0f, 0.0f), 383.0f);
            float y0f = floorf(y);
            float wy  = y - y0f;
            Ay[v] = 1.0f - wy; By[v] = wy;
        }
    }
    {   // center x (d == 0): runtime floor cell
        const float g = (float)flowx;
        float x   = fminf(fmaxf((g + 1.0f) * 0.5f * 383.0f, 0.0f), 383.0f);
        float x0f = floorf(x);
        float wx  = x - x0f;
        dXc = (int)x0f - j + 1;                 // 0 or 1
        Axc = 1.0f - wx; Bxc = wx;
        ax2[0] = dXc ? 0.0f : Axc;
        ax2[1] = dXc ? Axc  : Bxc;
        ax2[2] = dXc ? Bxc  : 0.0f;
    }
    {   // center y
        const float g = (float)flowy;
        float y   = fminf(fmaxf((g + 1.0f) * 0.5f * 383.0f, 0.0f), 383.0f);
        float y0f = floorf(y);
        float wy  = y - y0f;
        dYc = (int)y0f - i + 1;
        Ayc = 1.0f - wy; Byc = wy;
        ay2[0] = dYc ? 0.0f : Ayc;
        ay2[1] = dYc ? Ayc  : Byc;
        ay2[2] = dYc ? Byc  : 0.0f;
    }

    // y-side is wave-uniform -> pin to SGPRs
#pragma unroll
    for (int v = 0; v < 5; ++v) {
        if (v == 2) continue;
        Ay[v] = rfl_f(Ay[v]); By[v] = rfl_f(By[v]);
    }
    ay2[0] = rfl_f(ay2[0]); ay2[1] = rfl_f(ay2[1]); ay2[2] = rfl_f(ay2[2]);
    Ayc = rfl_f(Ayc); Byc = rfl_f(Byc);
    dYc = __builtin_amdgcn_readfirstlane(dYc);

    // clamped neighborhood offsets
    const int jm = max(j - 1, 0), jp = min(j + 1, W - 1);
    const int im = max(i - 1, 0), ip = min(i + 1, H - 1);
    const int rowoff[3] = { im * W, i * W, ip * W };   // uniform
    const int colx[3]   = { jm, j, jp };               // per-lane
    // middle-layer 2x2 selected positions
    const int mc0 = dXc ? j      : jm;
    const int mc1 = dXc ? jp     : j;
    const int mr0 = dYc ? i * W  : im * W;             // uniform
    const int mr1 = dYc ? ip * W : i * W;              // uniform

    float acc[A2];
#pragma unroll
    for (int a = 0; a < A2; ++a) acc[a] = 0.0f;

    // double-buffered neighborhoods (all indices compile-time after unroll)
    float n0[2][3][3];   // layer 0, 3x3
    float n2[2][3][3];   // layer 2, 3x3
    float nm[2][2][2];   // middle layer, 2x2

#define LOADN(buf, r_)                                                        \
    {                                                                         \
        const int ch = (r_) * 3 + c;                                          \
        const float* pl0 = layers + (size_t)(ch) * HW;                        \
        const float* pl1 = layers + (size_t)(12 + ch) * HW;                   \
        const float* pl2 = layers + (size_t)(24 + ch) * HW;                   \
        _Pragma("unroll")                                                     \
        for (int dy = 0; dy < 3; ++dy) {                                      \
            const float* r0 = pl0 + rowoff[dy];                               \
            const float* r2 = pl2 + rowoff[dy];                               \
            _Pragma("unroll")                                                 \
            for (int dx = 0; dx < 3; ++dx) {                                  \
                n0[buf][dy][dx] = r0[colx[dx]];                               \
                n2[buf][dy][dx] = r2[colx[dx]];                               \
            }                                                                 \
        }                                                                     \
        nm[buf][0][0] = pl1[mr0 + mc0];                                       \
        nm[buf][0][1] = pl1[mr0 + mc1];                                       \
        nm[buf][1][0] = pl1[mr1 + mc0];                                       \
        nm[buf][1][1] = pl1[mr1 + mc1];                                       \
    }

    LOADN(0, 0)

#pragma unroll
    for (int r = 0; r < 4; ++r) {
        const int cur = r & 1;
        if (r < 3) LOADN((r + 1) & 1, r + 1)

        // middle-layer sample (2x2 at runtime-selected cell; weights (Axc,Bxc))
        float v1;
        {
            float t0 = Axc * nm[cur][0][0] + Bxc * nm[cur][0][1];
            float t1 = Axc * nm[cur][1][0] + Bxc * nm[cur][1][1];
            v1 = Ayc * t0 + Byc * t1;
        }

#pragma unroll
        for (int al = 0; al < 5; ++al) {
            const int ml = 4 - al;               // mirrored shift for layer 2
            float h0[3], h2[3];
#pragma unroll
            for (int dy = 0; dy < 3; ++dy) {
                float x0d, x2d;
                if (al < 2)
                    x0d = Ax[al] * n0[cur][dy][0] + Bx[al] * n0[cur][dy][1];
                else if (al == 2)
                    x0d = ax2[0] * n0[cur][dy][0] + ax2[1] * n0[cur][dy][1] + ax2[2] * n0[cur][dy][2];
                else
                    x0d = Ax[al] * n0[cur][dy][1] + Bx[al] * n0[cur][dy][2];
                if (ml < 2)
                    x2d = Ax[ml] * n2[cur][dy][0] + Bx[ml] * n2[cur][dy][1];
                else if (ml == 2)
                    x2d = ax2[0] * n2[cur][dy][0] + ax2[1] * n2[cur][dy][1] + ax2[2] * n2[cur][dy][2];
                else
                    x2d = Ax[ml] * n2[cur][dy][1] + Bx[ml] * n2[cur][dy][2];
                h0[dy] = x0d * v1;               // fold v1 (same order as R2/R3)
                h2[dy] = x2d;
            }
#pragma unroll
            for (int ak = 0; ak < 5; ++ak) {
                const int mk = 4 - ak;
                float s0, s2;
                if (ak < 2)       s0 = Ay[ak] * h0[0] + By[ak] * h0[1];
                else if (ak == 2) s0 = ay2[0] * h0[0] + ay2[1] * h0[1] + ay2[2] * h0[2];
                else              s0 = Ay[ak] * h0[1] + By[ak] * h0[2];
                if (mk < 2)       s2 = Ay[mk] * h2[0] + By[mk] * h2[1];
                else if (mk == 2) s2 = ay2[0] * h2[0] + ay2[1] * h2[1] + ay2[2] * h2[2];
                else              s2 = Ay[mk] * h2[1] + By[mk] * h2[2];
                acc[ak * 5 + al] += s0 * s2;     // s0 carries v1
            }
        }
    }
#undef LOADN

    // out[a][c][i][j], mean over rank = 0.25 * sum
    const int pix = i * W + j;
    float* ob = out + (size_t)c * HW;
#pragma unroll
    for (int a = 0; a < A2; ++a) {
        float* pa = ob + (size_t)a * (3 * HW);   // uniform base
        pa[pix] = 0.25f * acc[a];
    }
}

extern "C" void kernel_launch(void* const* d_in, const int* in_sizes, int n_in,
                              void* d_out, int out_size, void* d_ws, size_t ws_size,
                              hipStream_t stream) {
    const float* layers = (const float*)d_in[0];   // [1,3,4,3,384,384] f32
    // d_in[1] (filters) unused: coordinates recomputed analytically (validated R2).
    float* out = (float*)d_out;                    // [1,25,3,384,384] f32

    const int n_blocks = HW / 64;                  // 2304 blocks of 192 threads
    multilayer_tap2<<<n_blocks, BLK, 0, stream>>>(layers, out);
}